// Round 3
// baseline (1163.110 us; speedup 1.0000x reference)
//
#include <hip/hip_runtime.h>

// Problem constants (from reference setup_inputs):
//   T = 8192 tokens, H = 4096 hidden, E = 64 experts, K = 2 top-k, D = 8 devices
// Output: [D, T, H] float32 -- out[d,t,:] = mask(d,t) ? input[t,:] : 0
// mask(d,t) = any_k( expert_mapping[expert_indices[t,k]] == d )

#define T_TOK 8192
#define H_DIM 4096
#define NUM_DEV 8
#define ROWS_PER_BLOCK 16   // 16 rows x 16 KiB = 256 KiB written per block
#define NBLOCKS ((NUM_DEV * T_TOK) / ROWS_PER_BLOCK)  // 4096

// Native clang vector type: __builtin_nontemporal_store requires a vector of
// scalars, not HIP's float4 class.
typedef float vfloat4 __attribute__((ext_vector_type(4)));

// R2 change: 16 rows per block instead of 1. The R1 kernel was latency-bound:
// each 1-row block paid a 2-deep dependent scalar-load chain (~400+ cyc) and
// an end-of-block vmcnt(0) store drain for only 16 KiB of work. Grid-stride
// over 16 rows amortizes both; partial unroll lets the compiler hoist the
// independent per-row scalar index loads and keep stores pipelined.
__global__ __launch_bounds__(256)
void a2a_dispatch_kernel(const float* __restrict__ input,
                         const int2* __restrict__ expert_indices,  // [T] int2
                         const int* __restrict__ expert_mapping,   // [E]
                         float* __restrict__ out)
{
    const unsigned tid  = threadIdx.x;
    const unsigned row0 = blockIdx.x * ROWS_PER_BLOCK;

#pragma unroll 4
    for (unsigned r = 0; r < ROWS_PER_BLOCK; ++r) {
        const unsigned row = row0 + r;             // in [0, D*T)
        const unsigned d   = row >> 13;            // row / T
        const unsigned t   = row & (T_TOK - 1);    // row % T

        // Wave-uniform -> scalar loads; tiny index data stays cache-resident.
        const int2 e    = expert_indices[t];
        const int  dev0 = expert_mapping[e.x];
        const int  dev1 = expert_mapping[e.y];
        const bool hit  = (dev0 == (int)d) | (dev1 == (int)d);

        const vfloat4* __restrict__ in_row =
            (const vfloat4*)(input + (size_t)t * H_DIM);
        vfloat4* __restrict__ out_row =
            (vfloat4*)(out + (size_t)row * H_DIM);

        if (hit) {
            // Cached loads (input reused ~1.9x across devices; 128 MiB fits in
            // L3); nontemporal stores keep the 1 GiB streaming output from
            // evicting it.
#pragma unroll
            for (int k = 0; k < 4; ++k) {
                vfloat4 v = in_row[tid + k * 256];
                __builtin_nontemporal_store(v, &out_row[tid + k * 256]);
            }
        } else {
            const vfloat4 z = (vfloat4)(0.f);
#pragma unroll
            for (int k = 0; k < 4; ++k) {
                __builtin_nontemporal_store(z, &out_row[tid + k * 256]);
            }
        }
    }
}

extern "C" void kernel_launch(void* const* d_in, const int* in_sizes, int n_in,
                              void* d_out, int out_size, void* d_ws, size_t ws_size,
                              hipStream_t stream) {
    const float* input          = (const float*)d_in[0];   // [T, H] fp32
    const int2*  expert_indices = (const int2*)d_in[1];    // [T, 2] int32
    const int*   expert_mapping = (const int*)d_in[2];     // [E]    int32
    float*       out            = (float*)d_out;           // [D, T, H] fp32

    a2a_dispatch_kernel<<<NBLOCKS, 256, 0, stream>>>(input, expert_indices,
                                                     expert_mapping, out);
}